// Round 1
// baseline (483.942 us; speedup 1.0000x reference)
//
#include <hip/hip_runtime.h>

#define N_NODES 50000
#define N_EDGES 800000
#define N_KEEP  25000
#define D       128

// ---------------- mask build ----------------
__global__ void zero_mask_kernel(unsigned int* __restrict__ mask) {
    int t = blockIdx.x * blockDim.x + threadIdx.x;
    if (t < N_NODES) mask[t] = 0u;
}

__global__ void set_mask_kernel(const int* __restrict__ idx,
                                unsigned int* __restrict__ mask) {
    int t = blockIdx.x * blockDim.x + threadIdx.x;
    if (t < N_KEEP) mask[idx[t]] = 1u;   // benign races, all write 1
}

// ---------------- linear: tx = x @ W^T + b; also init sums=tx, cnt=1 ----------------
__global__ __launch_bounds__(256) void linear_kernel(
    const float* __restrict__ x, const float* __restrict__ W,
    const float* __restrict__ b, float* __restrict__ tx,
    float* __restrict__ sums, float* __restrict__ cnt)
{
    // Ws[k*D + d] = W[d*D + k]  (transposed: lane-consecutive d -> consecutive
    // LDS addresses -> conflict-free reads in the k-loop)
    __shared__ float Ws[D * D];          // 64 KiB
    for (int i = threadIdx.x; i < D * D; i += blockDim.x) {
        int d = i >> 7, k = i & 127;     // coalesced global read of W
        Ws[k * D + d] = W[i];
    }
    __syncthreads();

    const int d = threadIdx.x & 127;     // output feature
    const int r = threadIdx.x >> 7;      // 0/1: two rows per block-iter
    const float bd = b[d];

    for (int n = blockIdx.x * 2 + r; n < N_NODES; n += gridDim.x * 2) {
        const float* xr = x + (size_t)n * D;   // wave-uniform row -> cached/broadcast
        float acc = bd;
        #pragma unroll 8
        for (int k = 0; k < D; ++k)
            acc += xr[k] * Ws[k * D + d];
        tx[(size_t)n * D + d]   = acc;
        sums[(size_t)n * D + d] = acc;     // self-loop contribution
        if (d == 0) cnt[n] = 1.0f;         // self-loop count
    }
}

// ---------------- scatter: one wave per edge, filtered by dst mask ----------------
__global__ __launch_bounds__(256) void scatter_kernel(
    const float* __restrict__ tx, const int* __restrict__ ei,
    const unsigned int* __restrict__ mask,
    float* __restrict__ sums, float* __restrict__ cnt)
{
    const int gw   = (int)((blockIdx.x * (unsigned)blockDim.x + threadIdx.x) >> 6);
    const int lane = threadIdx.x & 63;
    if (gw >= N_EDGES) return;

    const int dst = ei[N_EDGES + gw];    // wave-uniform load
    if (!mask[dst]) return;              // ~61% of edges skipped
    const int src = ei[gw];

    const float2 v = ((const float2*)(tx + (size_t)src * D))[lane];
    float* srow = sums + (size_t)dst * D + lane * 2;
    atomicAdd(srow,     v.x);
    atomicAdd(srow + 1, v.y);
    if (lane == 0) atomicAdd(cnt + dst, 1.0f);
}

// ---------------- finalize: h[idx] = sums[idx]/cnt[idx]; echo idx ----------------
__global__ void finalize_kernel(const float* __restrict__ sums,
                                const float* __restrict__ cnt,
                                const int* __restrict__ idx,
                                float* __restrict__ out)
{
    int t = blockIdx.x * blockDim.x + threadIdx.x;
    const int total = N_KEEP * (D / 4);         // one float4 per thread
    if (t < total) {
        int i = t >> 5;                          // row in [0, N_KEEP)
        int c = t & 31;                          // float4 within row
        int n = idx[i];
        float inv = 1.0f / cnt[n];
        float4 v = ((const float4*)(sums + (size_t)n * D))[c];
        v.x *= inv; v.y *= inv; v.z *= inv; v.w *= inv;
        ((float4*)(out + (size_t)i * D))[c] = v;
    }
    if (t < N_KEEP) {
        // second tuple output: idx, stored as float (exact for |idx| < 2^24)
        out[(size_t)N_KEEP * D + t] = (float)idx[t];
    }
}

extern "C" void kernel_launch(void* const* d_in, const int* in_sizes, int n_in,
                              void* d_out, int out_size, void* d_ws, size_t ws_size,
                              hipStream_t stream)
{
    const float* x   = (const float*)d_in[0];
    const int*   ei  = (const int*)d_in[1];
    const int*   idx = (const int*)d_in[2];
    const float* W   = (const float*)d_in[3];
    const float* b   = (const float*)d_in[4];
    float* out = (float*)d_out;

    char* ws = (char*)d_ws;
    const size_t TX_BYTES = (size_t)N_NODES * D * sizeof(float);   // 25.6 MB
    float*        tx   = (float*)(ws);
    float*        sums = (float*)(ws + TX_BYTES);
    float*        cnt  = (float*)(ws + 2 * TX_BYTES);
    unsigned int* mask = (unsigned int*)(ws + 2 * TX_BYTES + (size_t)N_NODES * 4);

    zero_mask_kernel<<<(N_NODES + 255) / 256, 256, 0, stream>>>(mask);
    set_mask_kernel<<<(N_KEEP + 255) / 256, 256, 0, stream>>>(idx, mask);
    linear_kernel<<<1024, 256, 0, stream>>>(x, W, b, tx, sums, cnt);
    scatter_kernel<<<(N_EDGES * 64) / 256, 256, 0, stream>>>(tx, ei, mask, sums, cnt);
    finalize_kernel<<<(N_KEEP * (D / 4) + 255) / 256, 256, 0, stream>>>(sums, cnt, idx, out);
}

// Round 2
// 365.515 us; speedup vs baseline: 1.3240x; 1.3240x over previous
//
#include <hip/hip_runtime.h>

#define N_NODES 50000
#define N_EDGES 800000
#define N_KEEP  25000
#define D       128

// ---------------- zero hist + mask ----------------
__global__ void zero_kernel(int* __restrict__ hist, unsigned int* __restrict__ mask) {
    int t = blockIdx.x * blockDim.x + threadIdx.x;
    if (t < N_NODES) { hist[t] = 0; mask[t] = 0u; }
}

__global__ void set_mask_kernel(const int* __restrict__ idx,
                                unsigned int* __restrict__ mask) {
    int t = blockIdx.x * blockDim.x + threadIdx.x;
    if (t < N_KEEP) mask[idx[t]] = 1u;   // benign races, all write 1
}

// ---------------- linear: tx = x @ W^T + b ----------------
__global__ __launch_bounds__(256) void linear_kernel(
    const float* __restrict__ x, const float* __restrict__ W,
    const float* __restrict__ b, float* __restrict__ tx)
{
    // Ws[k*D + d] = W[d*D + k]  (transposed for conflict-free k-loop reads)
    __shared__ float Ws[D * D];          // 64 KiB
    for (int i = threadIdx.x; i < D * D; i += blockDim.x) {
        int d = i >> 7, k = i & 127;
        Ws[k * D + d] = W[i];
    }
    __syncthreads();

    const int d = threadIdx.x & 127;
    const int r = threadIdx.x >> 7;
    const float bd = b[d];

    for (int n = blockIdx.x * 2 + r; n < N_NODES; n += gridDim.x * 2) {
        const float* xr = x + (size_t)n * D;
        float acc = bd;
        #pragma unroll 8
        for (int k = 0; k < D; ++k)
            acc += xr[k] * Ws[k * D + d];
        tx[(size_t)n * D + d] = acc;
    }
}

// ---------------- histogram of masked in-degrees ----------------
__global__ void hist_kernel(const int* __restrict__ ei,
                            const unsigned int* __restrict__ mask,
                            int* __restrict__ hist) {
    int e = blockIdx.x * blockDim.x + threadIdx.x;
    if (e < N_EDGES) {
        int dst = ei[N_EDGES + e];
        if (mask[dst]) atomicAdd(&hist[dst], 1);
    }
}

// ---------------- single-block exclusive scan: hist -> rowptr (+cursor copy) ----------------
__global__ __launch_bounds__(1024) void scan_kernel(const int* __restrict__ hist,
                                                    int* __restrict__ rowptr,
                                                    int* __restrict__ cursor) {
    __shared__ int part[1024];
    const int C = (N_NODES + 1023) / 1024;       // 49
    const int t = threadIdx.x;
    const int beg = t * C;
    const int end = (beg + C < N_NODES) ? beg + C : N_NODES;
    int s = 0;
    for (int i = beg; i < end; ++i) s += hist[i];
    part[t] = s;
    __syncthreads();
    for (int off = 1; off < 1024; off <<= 1) {    // Hillis-Steele inclusive
        int v = (t >= off) ? part[t - off] : 0;
        __syncthreads();
        part[t] += v;
        __syncthreads();
    }
    int run = part[t] - s;                        // exclusive chunk offset
    for (int i = beg; i < end; ++i) {
        rowptr[i] = run; cursor[i] = run;
        run += hist[i];
    }
    if (t == 1023) rowptr[N_NODES] = part[1023];
}

// ---------------- fill CSR column indices (masked edges only) ----------------
__global__ void fill_kernel(const int* __restrict__ ei,
                            const unsigned int* __restrict__ mask,
                            int* __restrict__ cursor,
                            int* __restrict__ colidx) {
    int e = blockIdx.x * blockDim.x + threadIdx.x;
    if (e < N_EDGES) {
        int dst = ei[N_EDGES + e];
        if (mask[dst]) {
            int p = atomicAdd(&cursor[dst], 1);
            colidx[p] = ei[e];
        }
    }
}

// ---------------- gather: one wave per output entry ----------------
__global__ __launch_bounds__(256) void gather_kernel(
    const float* __restrict__ tx, const int* __restrict__ rowptr,
    const int* __restrict__ colidx, const int* __restrict__ idx,
    float* __restrict__ out)
{
    const int gw   = (int)((blockIdx.x * (unsigned)blockDim.x + threadIdx.x) >> 6);
    const int lane = threadIdx.x & 63;
    if (gw >= N_KEEP) return;

    const int n   = idx[gw];                       // wave-uniform
    const int beg = rowptr[n];
    const int end = rowptr[n + 1];

    float2 acc = ((const float2*)(tx + (size_t)n * D))[lane];   // self-loop

    for (int base = beg; base < end; base += 64) {
        const int m   = end - base;
        const int lim = m < 64 ? m : 64;
        int s = (lane < lim) ? colidx[base + lane] : 0;          // coalesced chunk
        for (int e = 0; e < lim; ++e) {
            int src = __shfl(s, e);                              // wave-uniform src
            float2 v = ((const float2*)(tx + (size_t)src * D))[lane];
            acc.x += v.x; acc.y += v.y;
        }
    }
    const float inv = 1.0f / (float)(end - beg + 1);
    acc.x *= inv; acc.y *= inv;
    ((float2*)(out + (size_t)gw * D))[lane] = acc;
    if (lane == 0) out[(size_t)N_KEEP * D + gw] = (float)n;      // echo idx
}

extern "C" void kernel_launch(void* const* d_in, const int* in_sizes, int n_in,
                              void* d_out, int out_size, void* d_ws, size_t ws_size,
                              hipStream_t stream)
{
    const float* x   = (const float*)d_in[0];
    const int*   ei  = (const int*)d_in[1];
    const int*   idx = (const int*)d_in[2];
    const float* W   = (const float*)d_in[3];
    const float* b   = (const float*)d_in[4];
    float* out = (float*)d_out;

    char* ws = (char*)d_ws;
    size_t off = 0;
    float* tx = (float*)(ws + off);          off += (size_t)N_NODES * D * sizeof(float); // 25.6 MB
    int* hist    = (int*)(ws + off);         off += (size_t)N_NODES * 4;
    int* rowptr  = (int*)(ws + off);         off += (size_t)(N_NODES + 1) * 4;
    int* cursor  = (int*)(ws + off);         off += (size_t)N_NODES * 4;
    unsigned int* mask = (unsigned int*)(ws + off); off += (size_t)N_NODES * 4;
    int* colidx  = (int*)(ws + off);         off += (size_t)N_EDGES * 4;                 // 3.2 MB

    zero_kernel<<<(N_NODES + 255) / 256, 256, 0, stream>>>(hist, mask);
    set_mask_kernel<<<(N_KEEP + 255) / 256, 256, 0, stream>>>(idx, mask);
    linear_kernel<<<1024, 256, 0, stream>>>(x, W, b, tx);
    hist_kernel<<<(N_EDGES + 255) / 256, 256, 0, stream>>>(ei, mask, hist);
    scan_kernel<<<1, 1024, 0, stream>>>(hist, rowptr, cursor);
    fill_kernel<<<(N_EDGES + 255) / 256, 256, 0, stream>>>(ei, mask, cursor, colidx);
    gather_kernel<<<(N_KEEP * 64 + 255) / 256, 256, 0, stream>>>(tx, rowptr, colidx, idx, out);
}

// Round 3
// 195.034 us; speedup vs baseline: 2.4813x; 1.8741x over previous
//
#include <hip/hip_runtime.h>

#define N_NODES 50000
#define N_EDGES 800000
#define N_KEEP  25000
#define D       128
#define HIST_PAD 51200           // 800 * 64, for int4 scan
#define N_TILES  3125            // 50000 / 16

typedef __bf16 bf16x8 __attribute__((ext_vector_type(8)));
typedef float  f32x4  __attribute__((ext_vector_type(4)));

static __device__ inline unsigned int pack_bf16x2(float a, float b) {
    union { __bf16 h[2]; unsigned int u; } p;
    p.h[0] = (__bf16)a; p.h[1] = (__bf16)b;
    return p.u;
}

// ---------------- zero hist + mask ----------------
__global__ void zero_kernel(int* __restrict__ hist, unsigned int* __restrict__ mask) {
    int t = blockIdx.x * blockDim.x + threadIdx.x;
    if (t < HIST_PAD) hist[t] = 0;
    if (t < N_NODES)  mask[t] = 0u;
}

__global__ void set_mask_kernel(const int* __restrict__ idx,
                                unsigned int* __restrict__ mask) {
    int t = blockIdx.x * blockDim.x + threadIdx.x;
    if (t < N_KEEP) mask[idx[t]] = 1u;
}

// ---------------- linear via bf16 MFMA: tx = bf16(x @ W^T + b) ----------------
// One wave per 16-row tile; per wave: 8 col-tiles x 4 K-steps of 16x16x32 MFMA.
// W staged in LDS as bf16 [128][128] with XOR swizzle on byte bits[6:4]
// (uint-index bits[4:2]) -> conflict-free staging writes AND ds_read_b128.
__global__ __launch_bounds__(256) void linear_mfma_kernel(
    const float* __restrict__ x, const float* __restrict__ W,
    const float* __restrict__ b, __bf16* __restrict__ tx)
{
    __shared__ unsigned int Ws32[D * 64];          // 32 KiB (bf16 pairs)
    #pragma unroll
    for (int it = 0; it < 32; ++it) {
        int p = it * 256 + threadIdx.x;            // pair index
        int d = p >> 6, kp = p & 63;
        float2 wv = ((const float2*)W)[p];         // coalesced
        Ws32[(d * 64 + kp) ^ ((d & 7) << 2)] = pack_bf16x2(wv.x, wv.y);
    }
    __syncthreads();

    const int tile = blockIdx.x * 4 + (threadIdx.x >> 6);
    if (tile >= N_TILES) return;
    const int lane = threadIdx.x & 63;
    const int row  = lane & 15;                    // A row / B col / C col
    const int g    = lane >> 4;                    // k-group / C row-group
    const int n0   = tile * 16;

    // A fragments: 8 contiguous k's per lane from row-major x, cvt to bf16
    const float* xbase = x + (size_t)(n0 + row) * D + g * 8;
    bf16x8 afr[4];
    #pragma unroll
    for (int kk = 0; kk < 4; ++kk) {
        float4 f0 = ((const float4*)(xbase + kk * 32))[0];
        float4 f1 = ((const float4*)(xbase + kk * 32))[1];
        bf16x8 a;
        a[0]=(__bf16)f0.x; a[1]=(__bf16)f0.y; a[2]=(__bf16)f0.z; a[3]=(__bf16)f0.w;
        a[4]=(__bf16)f1.x; a[5]=(__bf16)f1.y; a[6]=(__bf16)f1.z; a[7]=(__bf16)f1.w;
        afr[kk] = a;
    }

    #pragma unroll
    for (int ct = 0; ct < 8; ++ct) {
        const int dcol = ct * 16 + row;            // W row = output col
        const float bv = b[dcol];
        f32x4 acc; acc[0]=bv; acc[1]=bv; acc[2]=bv; acc[3]=bv;
        #pragma unroll
        for (int kk = 0; kk < 4; ++kk) {
            int uidx = dcol * 64 + ((kk * 16 + g * 4) ^ ((dcol & 7) << 2));
            union { uint4 u; bf16x8 v; } wf;
            wf.u = *(const uint4*)&Ws32[uidx];     // ds_read_b128, swizzled
            acc = __builtin_amdgcn_mfma_f32_16x16x32_bf16(afr[kk], wf.v, acc, 0, 0, 0);
        }
        #pragma unroll
        for (int r = 0; r < 4; ++r)                // C: col=lane&15, row=g*4+r
            tx[(size_t)(n0 + g * 4 + r) * D + dcol] = (__bf16)acc[r];
    }
}

// ---------------- histogram of masked in-degrees ----------------
__global__ void hist_kernel(const int* __restrict__ ei,
                            const unsigned int* __restrict__ mask,
                            int* __restrict__ hist) {
    int e = blockIdx.x * blockDim.x + threadIdx.x;
    if (e < N_EDGES) {
        int dst = ei[N_EDGES + e];
        if (mask[dst]) atomicAdd(&hist[dst], 1);
    }
}

// ---------------- single-block scan: hist -> rowptr (+cursor) ----------------
__global__ __launch_bounds__(1024) void scan_kernel(const int* __restrict__ hist,
                                                    int* __restrict__ rowptr,
                                                    int* __restrict__ cursor) {
    __shared__ int part[1024];
    const int t = threadIdx.x;
    const int beg = t * 64;                        // threads 0..799 active
    int s = 0;
    if (t < 800) {
        #pragma unroll
        for (int i = 0; i < 16; ++i) {
            int4 v = ((const int4*)(hist + beg))[i];
            s += v.x + v.y + v.z + v.w;
        }
    }
    part[t] = s;
    __syncthreads();
    for (int off = 1; off < 1024; off <<= 1) {     // Hillis-Steele inclusive
        int v = (t >= off) ? part[t - off] : 0;
        __syncthreads();
        part[t] += v;
        __syncthreads();
    }
    if (t < 800) {
        int run = part[t] - s;                     // exclusive offset
        int end = (beg + 64 < N_NODES) ? beg + 64 : N_NODES;
        for (int i = beg; i < end; ++i) {
            rowptr[i] = run; cursor[i] = run;
            run += hist[i];
        }
    }
    if (t == 1023) rowptr[N_NODES] = part[1023];
}

// ---------------- fill CSR column indices (masked edges only) ----------------
__global__ void fill_kernel(const int* __restrict__ ei,
                            const unsigned int* __restrict__ mask,
                            int* __restrict__ cursor,
                            int* __restrict__ colidx) {
    int e = blockIdx.x * blockDim.x + threadIdx.x;
    if (e < N_EDGES) {
        int dst = ei[N_EDGES + e];
        if (mask[dst]) {
            int p = atomicAdd(&cursor[dst], 1);
            colidx[p] = ei[e];
        }
    }
}

// ---------------- gather: one wave per output entry, bf16 tx ----------------
__global__ __launch_bounds__(256) void gather_kernel(
    const __bf16* __restrict__ tx, const int* __restrict__ rowptr,
    const int* __restrict__ colidx, const int* __restrict__ idx,
    float* __restrict__ out)
{
    const int gw   = (int)((blockIdx.x * (unsigned)blockDim.x + threadIdx.x) >> 6);
    const int lane = threadIdx.x & 63;
    if (gw >= N_KEEP) return;

    const int n   = idx[gw];                       // wave-uniform
    const int beg = rowptr[n];
    const int end = rowptr[n + 1];

    unsigned int v = ((const unsigned int*)(tx + (size_t)n * D))[lane];  // self-loop
    float accx = __uint_as_float(v << 16);
    float accy = __uint_as_float(v & 0xffff0000u);

    for (int base = beg; base < end; base += 64) {
        const int m   = end - base;
        const int lim = m < 64 ? m : 64;
        int s = (lane < lim) ? colidx[base + lane] : 0;
        for (int e = 0; e < lim; ++e) {
            int src = __shfl(s, e);
            unsigned int u = ((const unsigned int*)(tx + (size_t)src * D))[lane];
            accx += __uint_as_float(u << 16);
            accy += __uint_as_float(u & 0xffff0000u);
        }
    }
    const float inv = 1.0f / (float)(end - beg + 1);
    float2 o; o.x = accx * inv; o.y = accy * inv;
    ((float2*)(out + (size_t)gw * D))[lane] = o;
    if (lane == 0) out[(size_t)N_KEEP * D + gw] = (float)n;   // echo idx
}

extern "C" void kernel_launch(void* const* d_in, const int* in_sizes, int n_in,
                              void* d_out, int out_size, void* d_ws, size_t ws_size,
                              hipStream_t stream)
{
    const float* x   = (const float*)d_in[0];
    const int*   ei  = (const int*)d_in[1];
    const int*   idx = (const int*)d_in[2];
    const float* W   = (const float*)d_in[3];
    const float* b   = (const float*)d_in[4];
    float* out = (float*)d_out;

    char* ws = (char*)d_ws;
    size_t off = 0;
    __bf16* tx = (__bf16*)(ws + off);        off += (size_t)N_NODES * D * 2;   // 12.8 MB
    int* hist    = (int*)(ws + off);         off += (size_t)HIST_PAD * 4;
    int* rowptr  = (int*)(ws + off);         off += (size_t)(N_NODES + 1) * 4;
    int* cursor  = (int*)(ws + off);         off += (size_t)N_NODES * 4;
    unsigned int* mask = (unsigned int*)(ws + off); off += (size_t)N_NODES * 4;
    int* colidx  = (int*)(ws + off);         off += (size_t)N_EDGES * 4;       // 3.2 MB

    zero_kernel<<<(HIST_PAD + 255) / 256, 256, 0, stream>>>(hist, mask);
    set_mask_kernel<<<(N_KEEP + 255) / 256, 256, 0, stream>>>(idx, mask);
    linear_mfma_kernel<<<(N_TILES + 3) / 4, 256, 0, stream>>>(x, W, b, tx);
    hist_kernel<<<(N_EDGES + 255) / 256, 256, 0, stream>>>(ei, mask, hist);
    scan_kernel<<<1, 1024, 0, stream>>>(hist, rowptr, cursor);
    fill_kernel<<<(N_EDGES + 255) / 256, 256, 0, stream>>>(ei, mask, cursor, colidx);
    gather_kernel<<<(N_KEEP * 64 + 255) / 256, 256, 0, stream>>>(tx, rowptr, colidx, idx, out);
}